// Round 12
// baseline (157.499 us; speedup 1.0000x reference)
//
#include <hip/hip_runtime.h>

// Problem constants: B=4, S=4096, D=1024, H=64
#define NS 4       // attention key-range splits (R12: 8->4, halves Opart traffic)

typedef __attribute__((ext_vector_type(8))) short sh8;  // 8 x bf16 (4 VGPRs)
typedef __attribute__((ext_vector_type(4))) short sh4;  // 4 x bf16 (8 B)
typedef __attribute__((ext_vector_type(4))) float f4;   // MFMA accumulator

// fold 1/sqrt(64) * log2(e) into Q so softmax is pure exp2
#define QSCALE 0.18033688011112042f

typedef const __attribute__((address_space(1))) unsigned int* gas_t;
typedef __attribute__((address_space(3))) unsigned int* las_t;
#define GLD16(g, l) __builtin_amdgcn_global_load_lds((gas_t)(g), (las_t)(l), 16, 0, 0)

static __device__ __forceinline__ unsigned short f2bf(float f) {
  unsigned u = __builtin_bit_cast(unsigned, f);
  u += 0x7fffu + ((u >> 16) & 1u);   // RNE
  return (unsigned short)(u >> 16);
}
static __device__ __forceinline__ float bf2f(unsigned short s) {
  unsigned u = ((unsigned)s) << 16;
  return __builtin_bit_cast(float, u);
}

// ---------------- kernel 1: Wt2 = W in MFMA B-fragment order ----------------
// Wt2[band][kt][lane][j] (bf16) band 0..11 (0-3 Q, 4-7 K, 8-11 V), kt 0..31,
// lane = q*16+l15 holds W[k = kt*32+q*8+j][col = band%4*16+l15].
__global__ __launch_bounds__(256) void wt_kernel(const float* __restrict__ Wq,
                                                 const float* __restrict__ Wk,
                                                 const float* __restrict__ Wv,
                                                 unsigned short* __restrict__ Wt2) {
  int blk = blockIdx.x;                 // 0..95
  int band = blk >> 3;                  // 0..11
  int widx = band >> 2;
  const float* W = widx == 0 ? Wq : (widx == 1 ? Wk : Wv);
  int ncol = (band & 3) * 16;
  int t = threadIdx.x;
  int kt = (blk & 7) * 4 + (t >> 6);    // 4 kt per block
  int lane = t & 63, q = lane >> 4, l15 = lane & 15;
  const float* src = W + (size_t)(kt * 32 + q * 8) * 64 + ncol + l15;
  sh8 o;
#pragma unroll
  for (int j = 0; j < 8; ++j) o[j] = (short)f2bf(src[(size_t)j * 64]);
  *(sh8*)&Wt2[((size_t)(band * 32 + kt) * 64 + lane) * 8] = o;
}

// ---------------- kernel 2: projection — quad-K stage (R10, best: 41.5 us; PARKED) ----------------
__global__ __launch_bounds__(256, 1) void proj_kernel(const float* __restrict__ in,
                                                      const unsigned short* __restrict__ Wt2,
                                                      unsigned short* __restrict__ Qg,
                                                      unsigned short* __restrict__ Kg,
                                                      unsigned short* __restrict__ Vtg) {
  __shared__ __align__(16) char lds[131072];
  int t = threadIdx.x;
  int w = t >> 6, lane = t & 63, q = lane >> 4, l15 = lane & 15;
  int m0 = blockIdx.x * 32;

  const float* ga = in + (size_t)(m0 + (w >> 1) * 16 + l15) * 1024 + q * 8 + (w & 1) * 4;
  const unsigned short* gb = Wt2 + (size_t)(w * 3) * 16384 + lane * 8;

  f4 acc[2][3];
  f4 z = {0.f, 0.f, 0.f, 0.f};
#pragma unroll
  for (int mt = 0; mt < 2; ++mt)
#pragma unroll
    for (int nt = 0; nt < 3; ++nt) acc[mt][nt] = z;

#define STAGE(s, buf)                                                         \
  {                                                                           \
    char* base = lds + (buf) * 65536;                                         \
    const float* gas = ga + (s) * 128;                                        \
    _Pragma("unroll")                                                         \
    for (int kk = 0; kk < 4; ++kk) {                                          \
      GLD16(gas + kk * 32, base + kk * 4096 + w * 1024);                      \
      _Pragma("unroll")                                                       \
      for (int nt = 0; nt < 3; ++nt)                                          \
        GLD16(gb + nt * 16384 + ((s) * 4 + kk) * 512,                         \
              base + 16384 + (kk * 12 + w * 3 + nt) * 1024);                  \
    }                                                                         \
  }

  STAGE(0, 0);
  for (int s = 0; s < 8; ++s) {
    int cur = s & 1;
    __syncthreads();
    if (s + 1 < 8) STAGE(s + 1, cur ^ 1);

    const f4* Af = (const f4*)(lds + cur * 65536);
    const sh8* Bf = (const sh8*)(lds + cur * 65536 + 16384);
#pragma unroll
    for (int kk = 0; kk < 4; ++kk) {
      sh8 bfr[3];
#pragma unroll
      for (int nt = 0; nt < 3; ++nt)
        bfr[nt] = Bf[(kk * 12 + w * 3 + nt) * 64 + lane];
#pragma unroll
      for (int mt = 0; mt < 2; ++mt) {
        f4 lo = Af[kk * 256 + mt * 128 + lane];
        f4 hi = Af[kk * 256 + mt * 128 + 64 + lane];
        sh8 a;
#pragma unroll
        for (int j = 0; j < 4; ++j) {
          a[j] = (short)f2bf(lo[j]);
          a[4 + j] = (short)f2bf(hi[j]);
        }
#pragma unroll
        for (int nt = 0; nt < 3; ++nt)
          acc[mt][nt] = __builtin_amdgcn_mfma_f32_16x16x32_bf16(a, bfr[nt], acc[mt][nt], 0, 0, 0);
      }
    }
  }
#undef STAGE

  float* vred = (float*)lds;   // [32][69] fp32
#pragma unroll
  for (int nt = 0; nt < 3; ++nt) {
    int band = w * 3 + nt;
#pragma unroll
    for (int mt = 0; mt < 2; ++mt)
#pragma unroll
      for (int r = 0; r < 4; ++r) {
        int row = mt * 16 + q * 4 + r;
        float v = acc[mt][nt][r];
        if (band < 4) {
          Qg[(size_t)(m0 + row) * 64 + band * 16 + l15] = f2bf(v * QSCALE);
        } else if (band < 8) {
          Kg[(size_t)(m0 + row) * 64 + (band - 4) * 16 + l15] = f2bf(v);
        } else {
          vred[row * 69 + (band - 8) * 16 + l15] = v;
        }
      }
  }
  __syncthreads();
  {
    int h = t >> 2, sl = (t & 3) * 8;
    int bb = m0 >> 12, s0 = m0 & 4095;
    sh8 vv;
#pragma unroll
    for (int j = 0; j < 8; ++j) vv[j] = (short)f2bf(vred[(sl + j) * 69 + h]);
    *(sh8*)&Vtg[(((size_t)(bb * 64 + h)) << 12) + s0 + sl] = vv;
  }
}

// ---------------- kernel 3: causal flash attention, S^T trick, split-K (R10 rev, NS=4) ----------------
__global__ __launch_bounds__(256, 4) void attn_split(const unsigned short* __restrict__ Qg,
                                                     const unsigned short* __restrict__ Kg,
                                                     const unsigned short* __restrict__ Vtg,
                                                     unsigned short* __restrict__ Opart,
                                                     float* __restrict__ Lpart) {
  __shared__ unsigned short Ks[64 * 72];
  __shared__ unsigned short Vs[64 * 72];
  __shared__ unsigned short Pw[4 * 16 * 72];
  int t = threadIdx.x;
  int b = blockIdx.y;
  int qt = 63 - (int)(blockIdx.x / NS);  // heavy q-tiles first (LPT)
  int sp = blockIdx.x % NS;
  int wave = t >> 6, lane = t & 63, quad = lane >> 4, l15 = lane & 15;
  unsigned short* Pws = Pw + wave * 16 * 72;

  int qrow0 = qt * 64 + wave * 16;
  size_t pbase = ((size_t)sp * 4 + b) * 4096;

  int nkt = qt + 1;
  int chunk = (nkt + NS - 1) / NS;
  int t0 = sp * chunk, t1 = min(nkt, t0 + chunk);
  if (t0 >= t1) {  // empty chunk: zero partials
#pragma unroll
    for (int r = 0; r < 4; ++r) {
      size_t row = pbase + qrow0 + quad * 4 + r;
#pragma unroll
      for (int ht = 0; ht < 4; ++ht) Opart[row * 64 + ht * 16 + l15] = 0;
      if (l15 == 0) Lpart[row] = 0.f;
    }
    return;
  }

  sh8 qa[2];
#pragma unroll
  for (int ks = 0; ks < 2; ++ks)
    qa[ks] = *(const sh8*)&Qg[(size_t)((b << 12) + qrow0 + l15) * 64 + ks * 32 + quad * 8];

  sh8 ones;
#pragma unroll
  for (int j = 0; j < 8; ++j) ones[j] = (short)0x3F80;  // bf16 1.0

  f4 o[5];  // o[0..3]: O accumulator; o[4]: row-sum (P * ones)
  f4 z = {0.f, 0.f, 0.f, 0.f};
#pragma unroll
  for (int ht = 0; ht < 5; ++ht) o[ht] = z;

  // staging geometry: thread covers chunks c0=t, c1=t+256; row=c>>3, off=(c&7)*8
  int r0 = t >> 3, o0 = (t & 7) * 8;
  int r1 = (t + 256) >> 3, o1 = ((t + 256) & 7) * 8;
  const unsigned short* kg0 = Kg + (size_t)((b << 12) + r0) * 64 + o0;
  const unsigned short* kg1 = Kg + (size_t)((b << 12) + r1) * 64 + o1;
  const unsigned short* vg0 = Vtg + (((size_t)(b * 64 + r0)) << 12) + o0;
  const unsigned short* vg1 = Vtg + (((size_t)(b * 64 + r1)) << 12) + o1;

  sh8 kr0, kr1, vr0, vr1;
  {
    size_t ko = (size_t)t0 * 64 * 64;
    kr0 = *(const sh8*)(kg0 + ko); kr1 = *(const sh8*)(kg1 + ko);
    vr0 = *(const sh8*)(vg0 + t0 * 64); vr1 = *(const sh8*)(vg1 + t0 * 64);
  }

  for (int kt = t0; kt < t1; ++kt) {
    __syncthreads();                      // prev-iter LDS reads done
    *(sh8*)&Ks[r0 * 72 + o0] = kr0;
    *(sh8*)&Ks[r1 * 72 + o1] = kr1;
    *(sh8*)&Vs[r0 * 72 + o0] = vr0;
    *(sh8*)&Vs[r1 * 72 + o1] = vr1;
    if (kt + 1 < t1) {                    // prefetch next tile into regs
      size_t ko = (size_t)(kt + 1) * 64 * 64;
      kr0 = *(const sh8*)(kg0 + ko); kr1 = *(const sh8*)(kg1 + ko);
      vr0 = *(const sh8*)(vg0 + (kt + 1) * 64); vr1 = *(const sh8*)(vg1 + (kt + 1) * 64);
    }
    __syncthreads();                      // Ks/Vs visible

    // S^T = K * Q^T: st[nt] lane(quad,l15) reg r = S[qrow0+l15][kt*64+nt*16+quad*4+r]
    f4 st[4];
#pragma unroll
    for (int nt = 0; nt < 4; ++nt) st[nt] = z;
#pragma unroll
    for (int ks = 0; ks < 2; ++ks) {
#pragma unroll
      for (int nt = 0; nt < 4; ++nt) {
        sh8 kb = *(const sh8*)&Ks[(nt * 16 + l15) * 72 + ks * 32 + quad * 8];
        st[nt] = __builtin_amdgcn_mfma_f32_16x16x32_bf16(kb, qa[ks], st[nt], 0, 0, 0);
      }
    }

    if (kt == nkt - 1) {  // causal mask on the global diagonal tile
      int qrow = qrow0 + l15;
#pragma unroll
      for (int nt = 0; nt < 4; ++nt) {
        int key0 = kt * 64 + nt * 16 + quad * 4;
#pragma unroll
        for (int r = 0; r < 4; ++r)
          if (key0 + r > qrow) st[nt][r] = -__builtin_inff();
      }
    }

    // static-max softmax: P = exp2(S); pack 4 contiguous keys -> one b64 LDS write
#pragma unroll
    for (int nt = 0; nt < 4; ++nt) {
      sh4 pk;
#pragma unroll
      for (int r = 0; r < 4; ++r) pk[r] = (short)f2bf(exp2f(st[nt][r]));
      *(sh4*)&Pws[l15 * 72 + nt * 16 + quad * 4] = pk;
    }
    asm volatile("s_waitcnt lgkmcnt(0)" ::: "memory");

#pragma unroll
    for (int ks = 0; ks < 2; ++ks) {
      sh8 pa = *(const sh8*)&Pws[l15 * 72 + ks * 32 + quad * 8];
#pragma unroll
      for (int ht = 0; ht < 4; ++ht) {
        sh8 vb = *(const sh8*)&Vs[(ht * 16 + l15) * 72 + ks * 32 + quad * 8];
        o[ht] = __builtin_amdgcn_mfma_f32_16x16x32_bf16(pa, vb, o[ht], 0, 0, 0);
      }
      o[4] = __builtin_amdgcn_mfma_f32_16x16x32_bf16(pa, ones, o[4], 0, 0, 0);
    }
  }

  // write partials (unnormalized O, bf16; L fp32)
#pragma unroll
  for (int r = 0; r < 4; ++r) {
    size_t row = pbase + qrow0 + quad * 4 + r;
#pragma unroll
    for (int ht = 0; ht < 4; ++ht)
      Opart[row * 64 + ht * 16 + l15] = f2bf(o[ht][r]);
    if (l15 == 0) Lpart[row] = o[4][r];
  }
}

// ---------------- kernel 4: combine split partials (vectorized, NS=4) ----------------
__global__ __launch_bounds__(256) void attn_combine(const unsigned short* __restrict__ Opart,
                                                    const float* __restrict__ Lpart,
                                                    float* __restrict__ out) {
  int t = threadIdx.x;
  int r = blockIdx.x * 32 + (t >> 3);   // global row 0..16383
  int h0 = (t & 7) * 8;
  float L = 0.f;
  float acc[8];
#pragma unroll
  for (int j = 0; j < 8; ++j) acc[j] = 0.f;
#pragma unroll
  for (int s = 0; s < NS; ++s) {
    L += Lpart[(size_t)s * 16384 + r];
    sh8 v = *(const sh8*)&Opart[((size_t)s * 16384 + r) * 64 + h0];
#pragma unroll
    for (int j = 0; j < 8; ++j) acc[j] += bf2f((unsigned short)v[j]);
  }
  float inv = 1.f / L;
  f4 o0, o1;
#pragma unroll
  for (int j = 0; j < 4; ++j) { o0[j] = acc[j] * inv; o1[j] = acc[4 + j] * inv; }
  *(f4*)&out[(size_t)r * 64 + h0] = o0;
  *(f4*)&out[(size_t)r * 64 + h0 + 4] = o1;
}

extern "C" void kernel_launch(void* const* d_in, const int* in_sizes, int n_in,
                              void* d_out, int out_size, void* d_ws, size_t ws_size,
                              hipStream_t stream) {
  const float* in = (const float*)d_in[0];
  const float* Wq = (const float*)d_in[1];
  const float* Wk = (const float*)d_in[2];
  const float* Wv = (const float*)d_in[3];
  float* out = (float*)d_out;

  char* ws = (char*)d_ws;
  unsigned short* Wt2   = (unsigned short*)ws;                 // 393,216 B
  unsigned short* Qg    = (unsigned short*)(ws + 393216);      // 2 MiB
  unsigned short* Kg    = (unsigned short*)(ws + 2490368);     // 2 MiB
  unsigned short* Vtg   = (unsigned short*)(ws + 4587520);     // 2 MiB
  unsigned short* Opart = (unsigned short*)(ws + 6684672);     // 8,388,608 B (NS=4)
  float*          Lpart = (float*)(ws + 23461888);             // 262,144 B
  // total ws use ~16 MiB

  hipLaunchKernelGGL(wt_kernel, dim3(96), dim3(256), 0, stream, Wq, Wk, Wv, Wt2);
  hipLaunchKernelGGL(proj_kernel, dim3(512), dim3(256), 0, stream, in, Wt2, Qg, Kg, Vtg);
  hipLaunchKernelGGL(attn_split, dim3(64 * NS, 4), dim3(256), 0, stream,
                     Qg, Kg, Vtg, Opart, Lpart);
  hipLaunchKernelGGL(attn_combine, dim3(512), dim3(256), 0, stream,
                     Opart, Lpart, out);
}

// Round 13
// 152.696 us; speedup vs baseline: 1.0315x; 1.0315x over previous
//
#include <hip/hip_runtime.h>

// Problem constants: B=4, S=4096, D=1024, H=64
#define NS 8       // attention key-range splits (NS=4 regressed: single-round LPT tail)

typedef __attribute__((ext_vector_type(8))) short sh8;  // 8 x bf16 (4 VGPRs)
typedef __attribute__((ext_vector_type(4))) short sh4;  // 4 x bf16 (8 B)
typedef __attribute__((ext_vector_type(4))) float f4;   // MFMA accumulator

// fold 1/sqrt(64) * log2(e) into Q so softmax is pure exp2
#define QSCALE 0.18033688011112042f

typedef const __attribute__((address_space(1))) unsigned int* gas_t;
typedef __attribute__((address_space(3))) unsigned int* las_t;
#define GLD16(g, l) __builtin_amdgcn_global_load_lds((gas_t)(g), (las_t)(l), 16, 0, 0)

static __device__ __forceinline__ unsigned short f2bf(float f) {
  unsigned u = __builtin_bit_cast(unsigned, f);
  u += 0x7fffu + ((u >> 16) & 1u);   // RNE
  return (unsigned short)(u >> 16);
}
static __device__ __forceinline__ float bf2f(unsigned short s) {
  unsigned u = ((unsigned)s) << 16;
  return __builtin_bit_cast(float, u);
}

// ---------------- kernel 1: Wt2 = W in MFMA B-fragment order ----------------
// Wt2[band][kt][lane][j] (bf16) band 0..11 (0-3 Q, 4-7 K, 8-11 V), kt 0..31,
// lane = q*16+l15 holds W[k = kt*32+q*8+j][col = band%4*16+l15].
__global__ __launch_bounds__(256) void wt_kernel(const float* __restrict__ Wq,
                                                 const float* __restrict__ Wk,
                                                 const float* __restrict__ Wv,
                                                 unsigned short* __restrict__ Wt2) {
  int blk = blockIdx.x;                 // 0..95
  int band = blk >> 3;                  // 0..11
  int widx = band >> 2;
  const float* W = widx == 0 ? Wq : (widx == 1 ? Wk : Wv);
  int ncol = (band & 3) * 16;
  int t = threadIdx.x;
  int kt = (blk & 7) * 4 + (t >> 6);    // 4 kt per block
  int lane = t & 63, q = lane >> 4, l15 = lane & 15;
  const float* src = W + (size_t)(kt * 32 + q * 8) * 64 + ncol + l15;
  sh8 o;
#pragma unroll
  for (int j = 0; j < 8; ++j) o[j] = (short)f2bf(src[(size_t)j * 64]);
  *(sh8*)&Wt2[((size_t)(band * 32 + kt) * 64 + lane) * 8] = o;
}

// ---------------- kernel 2: projection — quad-K stage (R10, best: 41.5 us; PARKED) ----------------
__global__ __launch_bounds__(256, 1) void proj_kernel(const float* __restrict__ in,
                                                      const unsigned short* __restrict__ Wt2,
                                                      unsigned short* __restrict__ Qg,
                                                      unsigned short* __restrict__ Kg,
                                                      unsigned short* __restrict__ Vtg) {
  __shared__ __align__(16) char lds[131072];
  int t = threadIdx.x;
  int w = t >> 6, lane = t & 63, q = lane >> 4, l15 = lane & 15;
  int m0 = blockIdx.x * 32;

  const float* ga = in + (size_t)(m0 + (w >> 1) * 16 + l15) * 1024 + q * 8 + (w & 1) * 4;
  const unsigned short* gb = Wt2 + (size_t)(w * 3) * 16384 + lane * 8;

  f4 acc[2][3];
  f4 z = {0.f, 0.f, 0.f, 0.f};
#pragma unroll
  for (int mt = 0; mt < 2; ++mt)
#pragma unroll
    for (int nt = 0; nt < 3; ++nt) acc[mt][nt] = z;

#define STAGE(s, buf)                                                         \
  {                                                                           \
    char* base = lds + (buf) * 65536;                                         \
    const float* gas = ga + (s) * 128;                                        \
    _Pragma("unroll")                                                         \
    for (int kk = 0; kk < 4; ++kk) {                                          \
      GLD16(gas + kk * 32, base + kk * 4096 + w * 1024);                      \
      _Pragma("unroll")                                                       \
      for (int nt = 0; nt < 3; ++nt)                                          \
        GLD16(gb + nt * 16384 + ((s) * 4 + kk) * 512,                         \
              base + 16384 + (kk * 12 + w * 3 + nt) * 1024);                  \
    }                                                                         \
  }

  STAGE(0, 0);
  for (int s = 0; s < 8; ++s) {
    int cur = s & 1;
    __syncthreads();
    if (s + 1 < 8) STAGE(s + 1, cur ^ 1);

    const f4* Af = (const f4*)(lds + cur * 65536);
    const sh8* Bf = (const sh8*)(lds + cur * 65536 + 16384);
#pragma unroll
    for (int kk = 0; kk < 4; ++kk) {
      sh8 bfr[3];
#pragma unroll
      for (int nt = 0; nt < 3; ++nt)
        bfr[nt] = Bf[(kk * 12 + w * 3 + nt) * 64 + lane];
#pragma unroll
      for (int mt = 0; mt < 2; ++mt) {
        f4 lo = Af[kk * 256 + mt * 128 + lane];
        f4 hi = Af[kk * 256 + mt * 128 + 64 + lane];
        sh8 a;
#pragma unroll
        for (int j = 0; j < 4; ++j) {
          a[j] = (short)f2bf(lo[j]);
          a[4 + j] = (short)f2bf(hi[j]);
        }
#pragma unroll
        for (int nt = 0; nt < 3; ++nt)
          acc[mt][nt] = __builtin_amdgcn_mfma_f32_16x16x32_bf16(a, bfr[nt], acc[mt][nt], 0, 0, 0);
      }
    }
  }
#undef STAGE

  float* vred = (float*)lds;   // [32][69] fp32
#pragma unroll
  for (int nt = 0; nt < 3; ++nt) {
    int band = w * 3 + nt;
#pragma unroll
    for (int mt = 0; mt < 2; ++mt)
#pragma unroll
      for (int r = 0; r < 4; ++r) {
        int row = mt * 16 + q * 4 + r;
        float v = acc[mt][nt][r];
        if (band < 4) {
          Qg[(size_t)(m0 + row) * 64 + band * 16 + l15] = f2bf(v * QSCALE);
        } else if (band < 8) {
          Kg[(size_t)(m0 + row) * 64 + (band - 4) * 16 + l15] = f2bf(v);
        } else {
          vred[row * 69 + (band - 8) * 16 + l15] = v;
        }
      }
  }
  __syncthreads();
  {
    int h = t >> 2, sl = (t & 3) * 8;
    int bb = m0 >> 12, s0 = m0 & 4095;
    sh8 vv;
#pragma unroll
    for (int j = 0; j < 8; ++j) vv[j] = (short)f2bf(vred[(sl + j) * 69 + h]);
    *(sh8*)&Vtg[(((size_t)(bb * 64 + h)) << 12) + s0 + sl] = vv;
  }
}

// ---------------- kernel 3: causal flash attention — QBLK=128, 8 waves, split-K ----------------
// R13: same 64-key tiles and staging volume, but 8 waves (128 q-rows) consume each
// staged K/V tile: MFMA work per barrier doubles (144/iter), total block-iterations
// halve (~8.3k -> ~4.2k), K/V re-read traffic halves. Occupancy preserved: 2 blocks
// x 8 waves = 16 waves/CU. LDS 36.9 KB. Causal mask applies to the last TWO k-tiles
// (per-wave key>qrow test; waves 0-3 fully mask the final tile, ~3% waste).
__global__ __launch_bounds__(512, 4) void attn_split(const unsigned short* __restrict__ Qg,
                                                     const unsigned short* __restrict__ Kg,
                                                     const unsigned short* __restrict__ Vtg,
                                                     unsigned short* __restrict__ Opart,
                                                     float* __restrict__ Lpart) {
  __shared__ unsigned short Ks[64 * 72];
  __shared__ unsigned short Vs[64 * 72];
  __shared__ unsigned short Pw[8 * 16 * 72];
  int t = threadIdx.x;
  int b = blockIdx.y;
  int qt2 = 31 - (int)(blockIdx.x >> 3);  // heavy q-supertiles first (LPT)
  int sp = blockIdx.x & 7;
  int wave = t >> 6, lane = t & 63, quad = lane >> 4, l15 = lane & 15;
  unsigned short* Pws = Pw + wave * 16 * 72;

  int qrow0 = qt2 * 128 + wave * 16;
  size_t pbase = ((size_t)sp * 4 + b) * 4096;

  int nkt = 2 * qt2 + 2;                  // 64-key tiles covering keys 0..qt2*128+127
  int chunk = (nkt + NS - 1) / NS;
  int t0 = sp * chunk, t1 = min(nkt, t0 + chunk);
  if (t0 >= t1) {  // empty chunk: zero partials
#pragma unroll
    for (int r = 0; r < 4; ++r) {
      size_t row = pbase + qrow0 + quad * 4 + r;
#pragma unroll
      for (int ht = 0; ht < 4; ++ht) Opart[row * 64 + ht * 16 + l15] = 0;
      if (l15 == 0) Lpart[row] = 0.f;
    }
    return;
  }

  sh8 qa[2];
#pragma unroll
  for (int ks = 0; ks < 2; ++ks)
    qa[ks] = *(const sh8*)&Qg[(size_t)((b << 12) + qrow0 + l15) * 64 + ks * 32 + quad * 8];

  sh8 ones;
#pragma unroll
  for (int j = 0; j < 8; ++j) ones[j] = (short)0x3F80;  // bf16 1.0

  f4 o[5];  // o[0..3]: O accumulator; o[4]: row-sum (P * ones)
  f4 z = {0.f, 0.f, 0.f, 0.f};
#pragma unroll
  for (int ht = 0; ht < 5; ++ht) o[ht] = z;

  // staging: 512 threads cover the 64x64 tile exactly: thread chunk row=t>>3,
  // off=(t&7)*8. One K chunk + one V chunk per thread.
  int r0 = t >> 3, o0 = (t & 7) * 8;
  const unsigned short* kg0 = Kg + (size_t)((b << 12) + r0) * 64 + o0;
  const unsigned short* vg0 = Vtg + (((size_t)(b * 64 + r0)) << 12) + o0;

  sh8 kr0, vr0;
  {
    kr0 = *(const sh8*)(kg0 + (size_t)t0 * 4096);
    vr0 = *(const sh8*)(vg0 + (size_t)t0 * 64);
  }

  for (int kt = t0; kt < t1; ++kt) {
    __syncthreads();                      // prev-iter LDS reads done
    *(sh8*)&Ks[r0 * 72 + o0] = kr0;
    *(sh8*)&Vs[r0 * 72 + o0] = vr0;
    if (kt + 1 < t1) {                    // prefetch next tile into regs
      kr0 = *(const sh8*)(kg0 + (size_t)(kt + 1) * 4096);
      vr0 = *(const sh8*)(vg0 + (size_t)(kt + 1) * 64);
    }
    __syncthreads();                      // Ks/Vs visible

    // S^T = K * Q^T: st[nt] lane(quad,l15) reg r = S[qrow0+l15][kt*64+nt*16+quad*4+r]
    f4 st[4];
#pragma unroll
    for (int nt = 0; nt < 4; ++nt) st[nt] = z;
#pragma unroll
    for (int ks = 0; ks < 2; ++ks) {
#pragma unroll
      for (int nt = 0; nt < 4; ++nt) {
        sh8 kb = *(const sh8*)&Ks[(nt * 16 + l15) * 72 + ks * 32 + quad * 8];
        st[nt] = __builtin_amdgcn_mfma_f32_16x16x32_bf16(kb, qa[ks], st[nt], 0, 0, 0);
      }
    }

    if (kt >= nkt - 2) {  // causal: diagonal spans the last two 64-key tiles
      int qrow = qrow0 + l15;
#pragma unroll
      for (int nt = 0; nt < 4; ++nt) {
        int key0 = kt * 64 + nt * 16 + quad * 4;
#pragma unroll
        for (int r = 0; r < 4; ++r)
          if (key0 + r > qrow) st[nt][r] = -__builtin_inff();
      }
    }

    // static-max softmax: P = exp2(S); pack 4 contiguous keys -> one b64 LDS write
#pragma unroll
    for (int nt = 0; nt < 4; ++nt) {
      sh4 pk;
#pragma unroll
      for (int r = 0; r < 4; ++r) pk[r] = (short)f2bf(exp2f(st[nt][r]));
      *(sh4*)&Pws[l15 * 72 + nt * 16 + quad * 4] = pk;
    }
    asm volatile("s_waitcnt lgkmcnt(0)" ::: "memory");

#pragma unroll
    for (int ks = 0; ks < 2; ++ks) {
      sh8 pa = *(const sh8*)&Pws[l15 * 72 + ks * 32 + quad * 8];
#pragma unroll
      for (int ht = 0; ht < 4; ++ht) {
        sh8 vb = *(const sh8*)&Vs[(ht * 16 + l15) * 72 + ks * 32 + quad * 8];
        o[ht] = __builtin_amdgcn_mfma_f32_16x16x32_bf16(pa, vb, o[ht], 0, 0, 0);
      }
      o[4] = __builtin_amdgcn_mfma_f32_16x16x32_bf16(pa, ones, o[4], 0, 0, 0);
    }
  }

  // write partials (unnormalized O, bf16; L fp32)
#pragma unroll
  for (int r = 0; r < 4; ++r) {
    size_t row = pbase + qrow0 + quad * 4 + r;
#pragma unroll
    for (int ht = 0; ht < 4; ++ht)
      Opart[row * 64 + ht * 16 + l15] = f2bf(o[ht][r]);
    if (l15 == 0) Lpart[row] = o[4][r];
  }
}

// ---------------- kernel 4: combine split partials (vectorized sh8 loads) ----------------
__global__ __launch_bounds__(256) void attn_combine(const unsigned short* __restrict__ Opart,
                                                    const float* __restrict__ Lpart,
                                                    float* __restrict__ out) {
  int t = threadIdx.x;
  int r = blockIdx.x * 32 + (t >> 3);   // global row 0..16383
  int h0 = (t & 7) * 8;
  float L = 0.f;
  float acc[8];
#pragma unroll
  for (int j = 0; j < 8; ++j) acc[j] = 0.f;
#pragma unroll
  for (int s = 0; s < NS; ++s) {
    L += Lpart[(size_t)s * 16384 + r];
    sh8 v = *(const sh8*)&Opart[((size_t)s * 16384 + r) * 64 + h0];
#pragma unroll
    for (int j = 0; j < 8; ++j) acc[j] += bf2f((unsigned short)v[j]);
  }
  float inv = 1.f / L;
  f4 o0, o1;
#pragma unroll
  for (int j = 0; j < 4; ++j) { o0[j] = acc[j] * inv; o1[j] = acc[4 + j] * inv; }
  *(f4*)&out[(size_t)r * 64 + h0] = o0;
  *(f4*)&out[(size_t)r * 64 + h0 + 4] = o1;
}

extern "C" void kernel_launch(void* const* d_in, const int* in_sizes, int n_in,
                              void* d_out, int out_size, void* d_ws, size_t ws_size,
                              hipStream_t stream) {
  const float* in = (const float*)d_in[0];
  const float* Wq = (const float*)d_in[1];
  const float* Wk = (const float*)d_in[2];
  const float* Wv = (const float*)d_in[3];
  float* out = (float*)d_out;

  char* ws = (char*)d_ws;
  unsigned short* Wt2   = (unsigned short*)ws;                 // 393,216 B
  unsigned short* Qg    = (unsigned short*)(ws + 393216);      // 2 MiB
  unsigned short* Kg    = (unsigned short*)(ws + 2490368);     // 2 MiB
  unsigned short* Vtg   = (unsigned short*)(ws + 4587520);     // 2 MiB
  unsigned short* Opart = (unsigned short*)(ws + 6684672);     // 16,777,216 B
  float*          Lpart = (float*)(ws + 23461888);             // 524,288 B
  // total ws use ~24 MiB

  hipLaunchKernelGGL(wt_kernel, dim3(96), dim3(256), 0, stream, Wq, Wk, Wv, Wt2);
  hipLaunchKernelGGL(proj_kernel, dim3(512), dim3(256), 0, stream, in, Wt2, Qg, Kg, Vtg);
  hipLaunchKernelGGL(attn_split, dim3(32 * NS, 4), dim3(512), 0, stream,
                     Qg, Kg, Vtg, Opart, Lpart);
  hipLaunchKernelGGL(attn_combine, dim3(512), dim3(256), 0, stream,
                     Opart, Lpart, out);
}

// Round 15
// 149.157 us; speedup vs baseline: 1.0559x; 1.0237x over previous
//
#include <hip/hip_runtime.h>

// Problem constants: B=4, S=4096, D=1024, H=64
#define NS 8       // attention key-range splits

typedef __attribute__((ext_vector_type(8))) short sh8;  // 8 x bf16 (4 VGPRs)
typedef __attribute__((ext_vector_type(4))) short sh4;  // 4 x bf16 (8 B)
typedef __attribute__((ext_vector_type(4))) float f4;   // MFMA accumulator

// fold 1/sqrt(64) * log2(e) into Q so softmax is pure exp2
#define QSCALE 0.18033688011112042f

typedef const __attribute__((address_space(1))) unsigned int* gas_t;
typedef __attribute__((address_space(3))) unsigned int* las_t;
#define GLD16(g, l) __builtin_amdgcn_global_load_lds((gas_t)(g), (las_t)(l), 16, 0, 0)

static __device__ __forceinline__ unsigned short f2bf(float f) {
  unsigned u = __builtin_bit_cast(unsigned, f);
  u += 0x7fffu + ((u >> 16) & 1u);   // RNE
  return (unsigned short)(u >> 16);
}
static __device__ __forceinline__ float bf2f(unsigned short s) {
  unsigned u = ((unsigned)s) << 16;
  return __builtin_bit_cast(float, u);
}

// ---------------- kernel 1: Wt2 = W in MFMA B-fragment order ----------------
// Wt2[band][kt][lane][j] (bf16) band 0..11 (0-3 Q, 4-7 K, 8-11 V), kt 0..31,
// lane = q*16+l15 holds W[k = kt*32+q*8+j][col = band%4*16+l15].
__global__ __launch_bounds__(256) void wt_kernel(const float* __restrict__ Wq,
                                                 const float* __restrict__ Wk,
                                                 const float* __restrict__ Wv,
                                                 unsigned short* __restrict__ Wt2) {
  int blk = blockIdx.x;                 // 0..95
  int band = blk >> 3;                  // 0..11
  int widx = band >> 2;
  const float* W = widx == 0 ? Wq : (widx == 1 ? Wk : Wv);
  int ncol = (band & 3) * 16;
  int t = threadIdx.x;
  int kt = (blk & 7) * 4 + (t >> 6);    // 4 kt per block
  int lane = t & 63, q = lane >> 4, l15 = lane & 15;
  const float* src = W + (size_t)(kt * 32 + q * 8) * 64 + ncol + l15;
  sh8 o;
#pragma unroll
  for (int j = 0; j < 8; ++j) o[j] = (short)f2bf(src[(size_t)j * 64]);
  *(sh8*)&Wt2[((size_t)(band * 32 + kt) * 64 + lane) * 8] = o;
}

// ---------------- kernel 2: projection — quad-K stage (R10, best: 41.5 us; PARKED) ----------------
__global__ __launch_bounds__(256, 1) void proj_kernel(const float* __restrict__ in,
                                                      const unsigned short* __restrict__ Wt2,
                                                      unsigned short* __restrict__ Qg,
                                                      unsigned short* __restrict__ Kg,
                                                      unsigned short* __restrict__ Vtg) {
  __shared__ __align__(16) char lds[131072];
  int t = threadIdx.x;
  int w = t >> 6, lane = t & 63, q = lane >> 4, l15 = lane & 15;
  int m0 = blockIdx.x * 32;

  const float* ga = in + (size_t)(m0 + (w >> 1) * 16 + l15) * 1024 + q * 8 + (w & 1) * 4;
  const unsigned short* gb = Wt2 + (size_t)(w * 3) * 16384 + lane * 8;

  f4 acc[2][3];
  f4 z = {0.f, 0.f, 0.f, 0.f};
#pragma unroll
  for (int mt = 0; mt < 2; ++mt)
#pragma unroll
    for (int nt = 0; nt < 3; ++nt) acc[mt][nt] = z;

#define STAGE(s, buf)                                                         \
  {                                                                           \
    char* base = lds + (buf) * 65536;                                         \
    const float* gas = ga + (s) * 128;                                        \
    _Pragma("unroll")                                                         \
    for (int kk = 0; kk < 4; ++kk) {                                          \
      GLD16(gas + kk * 32, base + kk * 4096 + w * 1024);                      \
      _Pragma("unroll")                                                       \
      for (int nt = 0; nt < 3; ++nt)                                          \
        GLD16(gb + nt * 16384 + ((s) * 4 + kk) * 512,                         \
              base + 16384 + (kk * 12 + w * 3 + nt) * 1024);                  \
    }                                                                         \
  }

  STAGE(0, 0);
  for (int s = 0; s < 8; ++s) {
    int cur = s & 1;
    __syncthreads();
    if (s + 1 < 8) STAGE(s + 1, cur ^ 1);

    const f4* Af = (const f4*)(lds + cur * 65536);
    const sh8* Bf = (const sh8*)(lds + cur * 65536 + 16384);
#pragma unroll
    for (int kk = 0; kk < 4; ++kk) {
      sh8 bfr[3];
#pragma unroll
      for (int nt = 0; nt < 3; ++nt)
        bfr[nt] = Bf[(kk * 12 + w * 3 + nt) * 64 + lane];
#pragma unroll
      for (int mt = 0; mt < 2; ++mt) {
        f4 lo = Af[kk * 256 + mt * 128 + lane];
        f4 hi = Af[kk * 256 + mt * 128 + 64 + lane];
        sh8 a;
#pragma unroll
        for (int j = 0; j < 4; ++j) {
          a[j] = (short)f2bf(lo[j]);
          a[4 + j] = (short)f2bf(hi[j]);
        }
#pragma unroll
        for (int nt = 0; nt < 3; ++nt)
          acc[mt][nt] = __builtin_amdgcn_mfma_f32_16x16x32_bf16(a, bfr[nt], acc[mt][nt], 0, 0, 0);
      }
    }
  }
#undef STAGE

  float* vred = (float*)lds;   // [32][69] fp32
#pragma unroll
  for (int nt = 0; nt < 3; ++nt) {
    int band = w * 3 + nt;
#pragma unroll
    for (int mt = 0; mt < 2; ++mt)
#pragma unroll
      for (int r = 0; r < 4; ++r) {
        int row = mt * 16 + q * 4 + r;
        float v = acc[mt][nt][r];
        if (band < 4) {
          Qg[(size_t)(m0 + row) * 64 + band * 16 + l15] = f2bf(v * QSCALE);
        } else if (band < 8) {
          Kg[(size_t)(m0 + row) * 64 + (band - 4) * 16 + l15] = f2bf(v);
        } else {
          vred[row * 69 + (band - 8) * 16 + l15] = v;
        }
      }
  }
  __syncthreads();
  {
    int h = t >> 2, sl = (t & 3) * 8;
    int bb = m0 >> 12, s0 = m0 & 4095;
    sh8 vv;
#pragma unroll
    for (int j = 0; j < 8; ++j) vv[j] = (short)f2bf(vred[(sl + j) * 69 + h]);
    *(sh8*)&Vtg[(((size_t)(bb * 64 + h)) << 12) + s0 + sl] = vv;
  }
}

// ---------------- kernel 3: causal flash attention (R10-exact + T5 setprio) ----------------
// R10 structure (best measured: 150.1 us total): 64-key tiles, 4 waves, NS=8, LPT.
// Added: s_setprio(1) around the MFMA clusters (T5). Evidence: +4-7% on attn with
// phase-diverse co-resident waves (m191); attn_split runs 4 blocks/CU at independent
// loop phases -> MFMA-entering waves get scheduler preference over staging waves.
__global__ __launch_bounds__(256, 4) void attn_split(const unsigned short* __restrict__ Qg,
                                                     const unsigned short* __restrict__ Kg,
                                                     const unsigned short* __restrict__ Vtg,
                                                     unsigned short* __restrict__ Opart,
                                                     float* __restrict__ Lpart) {
  __shared__ unsigned short Ks[64 * 72];
  __shared__ unsigned short Vs[64 * 72];
  __shared__ unsigned short Pw[4 * 16 * 72];
  int t = threadIdx.x;
  int b = blockIdx.y;
  int qt = 63 - (int)(blockIdx.x >> 3);  // heavy q-tiles first (LPT)
  int sp = blockIdx.x & 7;
  int wave = t >> 6, lane = t & 63, quad = lane >> 4, l15 = lane & 15;
  unsigned short* Pws = Pw + wave * 16 * 72;

  int qrow0 = qt * 64 + wave * 16;
  size_t pbase = ((size_t)sp * 4 + b) * 4096;

  int nkt = qt + 1;
  int chunk = (nkt + NS - 1) / NS;
  int t0 = sp * chunk, t1 = min(nkt, t0 + chunk);
  if (t0 >= t1) {  // empty chunk: zero partials
#pragma unroll
    for (int r = 0; r < 4; ++r) {
      size_t row = pbase + qrow0 + quad * 4 + r;
#pragma unroll
      for (int ht = 0; ht < 4; ++ht) Opart[row * 64 + ht * 16 + l15] = 0;
      if (l15 == 0) Lpart[row] = 0.f;
    }
    return;
  }

  sh8 qa[2];
#pragma unroll
  for (int ks = 0; ks < 2; ++ks)
    qa[ks] = *(const sh8*)&Qg[(size_t)((b << 12) + qrow0 + l15) * 64 + ks * 32 + quad * 8];

  sh8 ones;
#pragma unroll
  for (int j = 0; j < 8; ++j) ones[j] = (short)0x3F80;  // bf16 1.0

  f4 o[5];  // o[0..3]: O accumulator; o[4]: row-sum (P * ones)
  f4 z = {0.f, 0.f, 0.f, 0.f};
#pragma unroll
  for (int ht = 0; ht < 5; ++ht) o[ht] = z;

  // staging geometry: thread covers chunks c0=t, c1=t+256; row=c>>3, off=(c&7)*8
  int r0 = t >> 3, o0 = (t & 7) * 8;
  int r1 = (t + 256) >> 3, o1 = ((t + 256) & 7) * 8;
  const unsigned short* kg0 = Kg + (size_t)((b << 12) + r0) * 64 + o0;
  const unsigned short* kg1 = Kg + (size_t)((b << 12) + r1) * 64 + o1;
  const unsigned short* vg0 = Vtg + (((size_t)(b * 64 + r0)) << 12) + o0;
  const unsigned short* vg1 = Vtg + (((size_t)(b * 64 + r1)) << 12) + o1;

  sh8 kr0, kr1, vr0, vr1;
  {
    size_t ko = (size_t)t0 * 64 * 64;
    kr0 = *(const sh8*)(kg0 + ko); kr1 = *(const sh8*)(kg1 + ko);
    vr0 = *(const sh8*)(vg0 + t0 * 64); vr1 = *(const sh8*)(vg1 + t0 * 64);
  }

  for (int kt = t0; kt < t1; ++kt) {
    __syncthreads();                      // prev-iter LDS reads done
    *(sh8*)&Ks[r0 * 72 + o0] = kr0;
    *(sh8*)&Ks[r1 * 72 + o1] = kr1;
    *(sh8*)&Vs[r0 * 72 + o0] = vr0;
    *(sh8*)&Vs[r1 * 72 + o1] = vr1;
    if (kt + 1 < t1) {                    // prefetch next tile into regs
      size_t ko = (size_t)(kt + 1) * 64 * 64;
      kr0 = *(const sh8*)(kg0 + ko); kr1 = *(const sh8*)(kg1 + ko);
      vr0 = *(const sh8*)(vg0 + (kt + 1) * 64); vr1 = *(const sh8*)(vg1 + (kt + 1) * 64);
    }
    __syncthreads();                      // Ks/Vs visible

    // S^T = K * Q^T: st[nt] lane(quad,l15) reg r = S[qrow0+l15][kt*64+nt*16+quad*4+r]
    f4 st[4];
#pragma unroll
    for (int nt = 0; nt < 4; ++nt) st[nt] = z;
    __builtin_amdgcn_s_setprio(1);
#pragma unroll
    for (int ks = 0; ks < 2; ++ks) {
#pragma unroll
      for (int nt = 0; nt < 4; ++nt) {
        sh8 kb = *(const sh8*)&Ks[(nt * 16 + l15) * 72 + ks * 32 + quad * 8];
        st[nt] = __builtin_amdgcn_mfma_f32_16x16x32_bf16(kb, qa[ks], st[nt], 0, 0, 0);
      }
    }
    __builtin_amdgcn_s_setprio(0);

    if (kt == nkt - 1) {  // causal mask on the global diagonal tile
      int qrow = qrow0 + l15;
#pragma unroll
      for (int nt = 0; nt < 4; ++nt) {
        int key0 = kt * 64 + nt * 16 + quad * 4;
#pragma unroll
        for (int r = 0; r < 4; ++r)
          if (key0 + r > qrow) st[nt][r] = -__builtin_inff();
      }
    }

    // static-max softmax: P = exp2(S); pack 4 contiguous keys -> one b64 LDS write
#pragma unroll
    for (int nt = 0; nt < 4; ++nt) {
      sh4 pk;
#pragma unroll
      for (int r = 0; r < 4; ++r) pk[r] = (short)f2bf(exp2f(st[nt][r]));
      *(sh4*)&Pws[l15 * 72 + nt * 16 + quad * 4] = pk;
    }
    asm volatile("s_waitcnt lgkmcnt(0)" ::: "memory");

    __builtin_amdgcn_s_setprio(1);
#pragma unroll
    for (int ks = 0; ks < 2; ++ks) {
      sh8 pa = *(const sh8*)&Pws[l15 * 72 + ks * 32 + quad * 8];
#pragma unroll
      for (int ht = 0; ht < 4; ++ht) {
        sh8 vb = *(const sh8*)&Vs[(ht * 16 + l15) * 72 + ks * 32 + quad * 8];
        o[ht] = __builtin_amdgcn_mfma_f32_16x16x32_bf16(pa, vb, o[ht], 0, 0, 0);
      }
      o[4] = __builtin_amdgcn_mfma_f32_16x16x32_bf16(pa, ones, o[4], 0, 0, 0);
    }
    __builtin_amdgcn_s_setprio(0);
  }

  // write partials (unnormalized O, bf16; L fp32)
#pragma unroll
  for (int r = 0; r < 4; ++r) {
    size_t row = pbase + qrow0 + quad * 4 + r;
#pragma unroll
    for (int ht = 0; ht < 4; ++ht)
      Opart[row * 64 + ht * 16 + l15] = f2bf(o[ht][r]);
    if (l15 == 0) Lpart[row] = o[4][r];
  }
}

// ---------------- kernel 4: combine split partials (vectorized sh8 loads) ----------------
__global__ __launch_bounds__(256) void attn_combine(const unsigned short* __restrict__ Opart,
                                                    const float* __restrict__ Lpart,
                                                    float* __restrict__ out) {
  int t = threadIdx.x;
  int r = blockIdx.x * 32 + (t >> 3);   // global row 0..16383
  int h0 = (t & 7) * 8;
  float L = 0.f;
  float acc[8];
#pragma unroll
  for (int j = 0; j < 8; ++j) acc[j] = 0.f;
#pragma unroll
  for (int s = 0; s < NS; ++s) {
    L += Lpart[(size_t)s * 16384 + r];
    sh8 v = *(const sh8*)&Opart[((size_t)s * 16384 + r) * 64 + h0];
#pragma unroll
    for (int j = 0; j < 8; ++j) acc[j] += bf2f((unsigned short)v[j]);
  }
  float inv = 1.f / L;
  f4 o0, o1;
#pragma unroll
  for (int j = 0; j < 4; ++j) { o0[j] = acc[j] * inv; o1[j] = acc[4 + j] * inv; }
  *(f4*)&out[(size_t)r * 64 + h0] = o0;
  *(f4*)&out[(size_t)r * 64 + h0 + 4] = o1;
}

extern "C" void kernel_launch(void* const* d_in, const int* in_sizes, int n_in,
                              void* d_out, int out_size, void* d_ws, size_t ws_size,
                              hipStream_t stream) {
  const float* in = (const float*)d_in[0];
  const float* Wq = (const float*)d_in[1];
  const float* Wk = (const float*)d_in[2];
  const float* Wv = (const float*)d_in[3];
  float* out = (float*)d_out;

  char* ws = (char*)d_ws;
  unsigned short* Wt2   = (unsigned short*)ws;                 // 393,216 B
  unsigned short* Qg    = (unsigned short*)(ws + 393216);      // 2 MiB
  unsigned short* Kg    = (unsigned short*)(ws + 2490368);     // 2 MiB
  unsigned short* Vtg   = (unsigned short*)(ws + 4587520);     // 2 MiB
  unsigned short* Opart = (unsigned short*)(ws + 6684672);     // 16,777,216 B
  float*          Lpart = (float*)(ws + 23461888);             // 524,288 B
  // total ws use ~24 MiB

  hipLaunchKernelGGL(wt_kernel, dim3(96), dim3(256), 0, stream, Wq, Wk, Wv, Wt2);
  hipLaunchKernelGGL(proj_kernel, dim3(512), dim3(256), 0, stream, in, Wt2, Qg, Kg, Vtg);
  hipLaunchKernelGGL(attn_split, dim3(64 * NS, 4), dim3(256), 0, stream,
                     Qg, Kg, Vtg, Opart, Lpart);
  hipLaunchKernelGGL(attn_combine, dim3(512), dim3(256), 0, stream,
                     Opart, Lpart, out);
}

// Round 16
// 148.189 us; speedup vs baseline: 1.0628x; 1.0065x over previous
//
#include <hip/hip_runtime.h>

// Problem constants: B=4, S=4096, D=1024, H=64
#define NS 8       // attention key-range splits

typedef __attribute__((ext_vector_type(8))) short sh8;  // 8 x bf16 (4 VGPRs)
typedef __attribute__((ext_vector_type(4))) short sh4;  // 4 x bf16 (8 B)
typedef __attribute__((ext_vector_type(4))) float f4;   // MFMA accumulator

// fold 1/sqrt(64) * log2(e) into Q so softmax is pure exp2
#define QSCALE 0.18033688011112042f

typedef const __attribute__((address_space(1))) unsigned int* gas_t;
typedef __attribute__((address_space(3))) unsigned int* las_t;
#define GLD16(g, l) __builtin_amdgcn_global_load_lds((gas_t)(g), (las_t)(l), 16, 0, 0)

static __device__ __forceinline__ unsigned short f2bf(float f) {
  unsigned u = __builtin_bit_cast(unsigned, f);
  u += 0x7fffu + ((u >> 16) & 1u);   // RNE
  return (unsigned short)(u >> 16);
}
static __device__ __forceinline__ float bf2f(unsigned short s) {
  unsigned u = ((unsigned)s) << 16;
  return __builtin_bit_cast(float, u);
}

// ---------------- kernel 1: Wt2 = W in MFMA B-fragment order ----------------
// Wt2[band][kt][lane][j] (bf16) band 0..11 (0-3 Q, 4-7 K, 8-11 V), kt 0..31,
// lane = q*16+l15 holds W[k = kt*32+q*8+j][col = band%4*16+l15].
__global__ __launch_bounds__(256) void wt_kernel(const float* __restrict__ Wq,
                                                 const float* __restrict__ Wk,
                                                 const float* __restrict__ Wv,
                                                 unsigned short* __restrict__ Wt2) {
  int blk = blockIdx.x;                 // 0..95
  int band = blk >> 3;                  // 0..11
  int widx = band >> 2;
  const float* W = widx == 0 ? Wq : (widx == 1 ? Wk : Wv);
  int ncol = (band & 3) * 16;
  int t = threadIdx.x;
  int kt = (blk & 7) * 4 + (t >> 6);    // 4 kt per block
  int lane = t & 63, q = lane >> 4, l15 = lane & 15;
  const float* src = W + (size_t)(kt * 32 + q * 8) * 64 + ncol + l15;
  sh8 o;
#pragma unroll
  for (int j = 0; j < 8; ++j) o[j] = (short)f2bf(src[(size_t)j * 64]);
  *(sh8*)&Wt2[((size_t)(band * 32 + kt) * 64 + lane) * 8] = o;
}

// ---------------- kernel 2: projection — M=64, BK=128, 8 barriers, full-LDS ----------------
// R16: R10's quad-K 8-stage structure with M doubled to 64. Effect vs R10:
//   staged bytes 256 MB -> 164 MB (B amortized over 2x rows),
//   stage-latencies per CU 16 -> 8 (grid 256 = one resident round at 1 block/CU),
//   MLP per stage 16 -> 20 GLD16s/thread, 48 MFMAs/wave/stage.
// LDS: per stage A 32KB ([kk 0..3][chunk 0..7][1KB]) + B 48KB ([kk][band][1KB])
// = 80KB; double-buffered = 163,840 B = the full 160 KiB CU allocation.
__global__ __launch_bounds__(256, 1) void proj_kernel(const float* __restrict__ in,
                                                      const unsigned short* __restrict__ Wt2,
                                                      unsigned short* __restrict__ Qg,
                                                      unsigned short* __restrict__ Kg,
                                                      unsigned short* __restrict__ Vtg) {
  __shared__ __align__(16) char lds[163840];
  int t = threadIdx.x;
  int w = t >> 6, lane = t & 63, q = lane >> 4, l15 = lane & 15;
  int m0 = blockIdx.x * 64;

  // A source: wave w owns rows m0+w*16..+15; chunk c = w*2+e covers seg e (floats
  // q*8+e*4..+4). Per kk, wave stages chunks w*2 and w*2+1.
  const float* ga = in + (size_t)(m0 + w * 16 + l15) * 1024 + q * 8;
  // B source: wave w stages/consumes bands w*3..w*3+2; fragment = 1KB contiguous
  const unsigned short* gb = Wt2 + (size_t)(w * 3) * 16384 + lane * 8;

  f4 acc[4][3];
  f4 z = {0.f, 0.f, 0.f, 0.f};
#pragma unroll
  for (int mt = 0; mt < 4; ++mt)
#pragma unroll
    for (int nt = 0; nt < 3; ++nt) acc[mt][nt] = z;

  // stage s covers k-steps s*4 .. s*4+3 (k = s*128 .. s*128+127)
#define STAGE(s, buf)                                                         \
  {                                                                           \
    char* base = lds + (buf) * 81920;                                         \
    const float* gas = ga + (s) * 128;                                        \
    _Pragma("unroll")                                                         \
    for (int kk = 0; kk < 4; ++kk) {                                          \
      GLD16(gas + kk * 32, base + kk * 8192 + (w * 2 + 0) * 1024);            \
      GLD16(gas + kk * 32 + 4, base + kk * 8192 + (w * 2 + 1) * 1024);        \
      _Pragma("unroll")                                                       \
      for (int nt = 0; nt < 3; ++nt)                                          \
        GLD16(gb + nt * 16384 + ((s) * 4 + kk) * 512,                         \
              base + 32768 + (kk * 12 + w * 3 + nt) * 1024);                  \
    }                                                                         \
  }

  STAGE(0, 0);
  for (int s = 0; s < 8; ++s) {
    int cur = s & 1;
    __syncthreads();
    if (s + 1 < 8) STAGE(s + 1, cur ^ 1);

    const f4* Af = (const f4*)(lds + cur * 81920);
    const sh8* Bf = (const sh8*)(lds + cur * 81920 + 32768);
#pragma unroll
    for (int kk = 0; kk < 4; ++kk) {
      sh8 bfr[3];
#pragma unroll
      for (int nt = 0; nt < 3; ++nt)
        bfr[nt] = Bf[(kk * 12 + w * 3 + nt) * 64 + lane];
#pragma unroll
      for (int mt = 0; mt < 4; ++mt) {
        f4 lo = Af[kk * 512 + (mt * 2 + 0) * 64 + lane];
        f4 hi = Af[kk * 512 + (mt * 2 + 1) * 64 + lane];
        sh8 a;
#pragma unroll
        for (int j = 0; j < 4; ++j) {
          a[j] = (short)f2bf(lo[j]);
          a[4 + j] = (short)f2bf(hi[j]);
        }
#pragma unroll
        for (int nt = 0; nt < 3; ++nt)
          acc[mt][nt] = __builtin_amdgcn_mfma_f32_16x16x32_bf16(a, bfr[nt], acc[mt][nt], 0, 0, 0);
      }
    }
  }
#undef STAGE

  // epilogue: band = w*3+nt; C row = mt*16+q*4+r, col = l15 within band.
  // bands 0-3 Q (scaled), 4-7 K, 8-11 V via LDS transpose. vred [64][69] fp32
  // (17.7KB) aliases buf0's A region only; last compute reads buf1 (s=7), and
  // buf0's final readers (stage-6 compute) drained at the s=7 barrier.
  float* vred = (float*)lds;
#pragma unroll
  for (int nt = 0; nt < 3; ++nt) {
    int band = w * 3 + nt;
#pragma unroll
    for (int mt = 0; mt < 4; ++mt)
#pragma unroll
      for (int r = 0; r < 4; ++r) {
        int row = mt * 16 + q * 4 + r;
        float v = acc[mt][nt][r];
        if (band < 4) {
          Qg[(size_t)(m0 + row) * 64 + band * 16 + l15] = f2bf(v * QSCALE);
        } else if (band < 8) {
          Kg[(size_t)(m0 + row) * 64 + (band - 4) * 16 + l15] = f2bf(v);
        } else {
          vred[row * 69 + (band - 8) * 16 + l15] = v;
        }
      }
  }
  __syncthreads();
  {
    int h = t >> 2, sl = (t & 3) * 16;    // h 0..63, 16 s-positions per thread
    int bb = m0 >> 12, s0 = m0 & 4095;
#pragma unroll
    for (int half = 0; half < 2; ++half) {
      sh8 vv;
#pragma unroll
      for (int j = 0; j < 8; ++j) vv[j] = (short)f2bf(vred[(sl + half * 8 + j) * 69 + h]);
      *(sh8*)&Vtg[(((size_t)(bb * 64 + h)) << 12) + s0 + sl + half * 8] = vv;
    }
  }
}

// ---------------- kernel 3: causal flash attention (R10 + T5 setprio; best) ----------------
__global__ __launch_bounds__(256, 4) void attn_split(const unsigned short* __restrict__ Qg,
                                                     const unsigned short* __restrict__ Kg,
                                                     const unsigned short* __restrict__ Vtg,
                                                     unsigned short* __restrict__ Opart,
                                                     float* __restrict__ Lpart) {
  __shared__ unsigned short Ks[64 * 72];
  __shared__ unsigned short Vs[64 * 72];
  __shared__ unsigned short Pw[4 * 16 * 72];
  int t = threadIdx.x;
  int b = blockIdx.y;
  int qt = 63 - (int)(blockIdx.x >> 3);  // heavy q-tiles first (LPT)
  int sp = blockIdx.x & 7;
  int wave = t >> 6, lane = t & 63, quad = lane >> 4, l15 = lane & 15;
  unsigned short* Pws = Pw + wave * 16 * 72;

  int qrow0 = qt * 64 + wave * 16;
  size_t pbase = ((size_t)sp * 4 + b) * 4096;

  int nkt = qt + 1;
  int chunk = (nkt + NS - 1) / NS;
  int t0 = sp * chunk, t1 = min(nkt, t0 + chunk);
  if (t0 >= t1) {  // empty chunk: zero partials
#pragma unroll
    for (int r = 0; r < 4; ++r) {
      size_t row = pbase + qrow0 + quad * 4 + r;
#pragma unroll
      for (int ht = 0; ht < 4; ++ht) Opart[row * 64 + ht * 16 + l15] = 0;
      if (l15 == 0) Lpart[row] = 0.f;
    }
    return;
  }

  sh8 qa[2];
#pragma unroll
  for (int ks = 0; ks < 2; ++ks)
    qa[ks] = *(const sh8*)&Qg[(size_t)((b << 12) + qrow0 + l15) * 64 + ks * 32 + quad * 8];

  sh8 ones;
#pragma unroll
  for (int j = 0; j < 8; ++j) ones[j] = (short)0x3F80;  // bf16 1.0

  f4 o[5];  // o[0..3]: O accumulator; o[4]: row-sum (P * ones)
  f4 z = {0.f, 0.f, 0.f, 0.f};
#pragma unroll
  for (int ht = 0; ht < 5; ++ht) o[ht] = z;

  // staging geometry: thread covers chunks c0=t, c1=t+256; row=c>>3, off=(c&7)*8
  int r0 = t >> 3, o0 = (t & 7) * 8;
  int r1 = (t + 256) >> 3, o1 = ((t + 256) & 7) * 8;
  const unsigned short* kg0 = Kg + (size_t)((b << 12) + r0) * 64 + o0;
  const unsigned short* kg1 = Kg + (size_t)((b << 12) + r1) * 64 + o1;
  const unsigned short* vg0 = Vtg + (((size_t)(b * 64 + r0)) << 12) + o0;
  const unsigned short* vg1 = Vtg + (((size_t)(b * 64 + r1)) << 12) + o1;

  sh8 kr0, kr1, vr0, vr1;
  {
    size_t ko = (size_t)t0 * 64 * 64;
    kr0 = *(const sh8*)(kg0 + ko); kr1 = *(const sh8*)(kg1 + ko);
    vr0 = *(const sh8*)(vg0 + t0 * 64); vr1 = *(const sh8*)(vg1 + t0 * 64);
  }

  for (int kt = t0; kt < t1; ++kt) {
    __syncthreads();                      // prev-iter LDS reads done
    *(sh8*)&Ks[r0 * 72 + o0] = kr0;
    *(sh8*)&Ks[r1 * 72 + o1] = kr1;
    *(sh8*)&Vs[r0 * 72 + o0] = vr0;
    *(sh8*)&Vs[r1 * 72 + o1] = vr1;
    if (kt + 1 < t1) {                    // prefetch next tile into regs
      size_t ko = (size_t)(kt + 1) * 64 * 64;
      kr0 = *(const sh8*)(kg0 + ko); kr1 = *(const sh8*)(kg1 + ko);
      vr0 = *(const sh8*)(vg0 + (kt + 1) * 64); vr1 = *(const sh8*)(vg1 + (kt + 1) * 64);
    }
    __syncthreads();                      // Ks/Vs visible

    // S^T = K * Q^T: st[nt] lane(quad,l15) reg r = S[qrow0+l15][kt*64+nt*16+quad*4+r]
    f4 st[4];
#pragma unroll
    for (int nt = 0; nt < 4; ++nt) st[nt] = z;
    __builtin_amdgcn_s_setprio(1);
#pragma unroll
    for (int ks = 0; ks < 2; ++ks) {
#pragma unroll
      for (int nt = 0; nt < 4; ++nt) {
        sh8 kb = *(const sh8*)&Ks[(nt * 16 + l15) * 72 + ks * 32 + quad * 8];
        st[nt] = __builtin_amdgcn_mfma_f32_16x16x32_bf16(kb, qa[ks], st[nt], 0, 0, 0);
      }
    }
    __builtin_amdgcn_s_setprio(0);

    if (kt == nkt - 1) {  // causal mask on the global diagonal tile
      int qrow = qrow0 + l15;
#pragma unroll
      for (int nt = 0; nt < 4; ++nt) {
        int key0 = kt * 64 + nt * 16 + quad * 4;
#pragma unroll
        for (int r = 0; r < 4; ++r)
          if (key0 + r > qrow) st[nt][r] = -__builtin_inff();
      }
    }

    // static-max softmax: P = exp2(S); pack 4 contiguous keys -> one b64 LDS write
#pragma unroll
    for (int nt = 0; nt < 4; ++nt) {
      sh4 pk;
#pragma unroll
      for (int r = 0; r < 4; ++r) pk[r] = (short)f2bf(exp2f(st[nt][r]));
      *(sh4*)&Pws[l15 * 72 + nt * 16 + quad * 4] = pk;
    }
    asm volatile("s_waitcnt lgkmcnt(0)" ::: "memory");

    __builtin_amdgcn_s_setprio(1);
#pragma unroll
    for (int ks = 0; ks < 2; ++ks) {
      sh8 pa = *(const sh8*)&Pws[l15 * 72 + ks * 32 + quad * 8];
#pragma unroll
      for (int ht = 0; ht < 4; ++ht) {
        sh8 vb = *(const sh8*)&Vs[(ht * 16 + l15) * 72 + ks * 32 + quad * 8];
        o[ht] = __builtin_amdgcn_mfma_f32_16x16x32_bf16(pa, vb, o[ht], 0, 0, 0);
      }
      o[4] = __builtin_amdgcn_mfma_f32_16x16x32_bf16(pa, ones, o[4], 0, 0, 0);
    }
    __builtin_amdgcn_s_setprio(0);
  }

  // write partials (unnormalized O, bf16; L fp32)
#pragma unroll
  for (int r = 0; r < 4; ++r) {
    size_t row = pbase + qrow0 + quad * 4 + r;
#pragma unroll
    for (int ht = 0; ht < 4; ++ht)
      Opart[row * 64 + ht * 16 + l15] = f2bf(o[ht][r]);
    if (l15 == 0) Lpart[row] = o[4][r];
  }
}

// ---------------- kernel 4: combine split partials (vectorized sh8 loads) ----------------
__global__ __launch_bounds__(256) void attn_combine(const unsigned short* __restrict__ Opart,
                                                    const float* __restrict__ Lpart,
                                                    float* __restrict__ out) {
  int t = threadIdx.x;
  int r = blockIdx.x * 32 + (t >> 3);   // global row 0..16383
  int h0 = (t & 7) * 8;
  float L = 0.f;
  float acc[8];
#pragma unroll
  for (int j = 0; j < 8; ++j) acc[j] = 0.f;
#pragma unroll
  for (int s = 0; s < NS; ++s) {
    L += Lpart[(size_t)s * 16384 + r];
    sh8 v = *(const sh8*)&Opart[((size_t)s * 16384 + r) * 64 + h0];
#pragma unroll
    for (int j = 0; j < 8; ++j) acc[j] += bf2f((unsigned short)v[j]);
  }
  float inv = 1.f / L;
  f4 o0, o1;
#pragma unroll
  for (int j = 0; j < 4; ++j) { o0[j] = acc[j] * inv; o1[j] = acc[4 + j] * inv; }
  *(f4*)&out[(size_t)r * 64 + h0] = o0;
  *(f4*)&out[(size_t)r * 64 + h0 + 4] = o1;
}

extern "C" void kernel_launch(void* const* d_in, const int* in_sizes, int n_in,
                              void* d_out, int out_size, void* d_ws, size_t ws_size,
                              hipStream_t stream) {
  const float* in = (const float*)d_in[0];
  const float* Wq = (const float*)d_in[1];
  const float* Wk = (const float*)d_in[2];
  const float* Wv = (const float*)d_in[3];
  float* out = (float*)d_out;

  char* ws = (char*)d_ws;
  unsigned short* Wt2   = (unsigned short*)ws;                 // 393,216 B
  unsigned short* Qg    = (unsigned short*)(ws + 393216);      // 2 MiB
  unsigned short* Kg    = (unsigned short*)(ws + 2490368);     // 2 MiB
  unsigned short* Vtg   = (unsigned short*)(ws + 4587520);     // 2 MiB
  unsigned short* Opart = (unsigned short*)(ws + 6684672);     // 16,777,216 B
  float*          Lpart = (float*)(ws + 23461888);             // 524,288 B
  // total ws use ~24 MiB

  hipLaunchKernelGGL(wt_kernel, dim3(96), dim3(256), 0, stream, Wq, Wk, Wv, Wt2);
  hipLaunchKernelGGL(proj_kernel, dim3(256), dim3(256), 0, stream, in, Wt2, Qg, Kg, Vtg);
  hipLaunchKernelGGL(attn_split, dim3(64 * NS, 4), dim3(256), 0, stream,
                     Qg, Kg, Vtg, Opart, Lpart);
  hipLaunchKernelGGL(attn_combine, dim3(512), dim3(256), 0, stream,
                     Opart, Lpart, out);
}